// Round 8
// baseline (20302.306 us; speedup 1.0000x reference)
//
#include <hip/hip_runtime.h>
#include <stdint.h>

#define BB 16
#define TT 1000
#define SZ 896
#define HF 448
#define NC 112            // compute WGs (pure matvec)
#define NWG 240           // 112 compute + 128 sampler (16 x (4 coarse + 4 fine))
#define LDS_FLOATS 30112
#define LDS_BYTES (LDS_FLOATS * 4)

typedef float f32x4 __attribute__((ext_vector_type(4)));
typedef float f32x2 __attribute__((ext_vector_type(2)));

// Persistent device-global state — ALL cross-WG data as (value, tag) 8B pairs.
__device__ float g_hc[BB * HF * 2];      // coarse hidden pairs [16][448][2]
__device__ float g_hf[BB * HF * 2];      // fine hidden pairs
__device__ float g_hpc[BB * HF * 8];     // coarse hp rows [16][448][{s0,t,s1,t,s2,t,p,p}]
__device__ float g_hpf[BB * HF * 8];     // fine hp rows
__device__ unsigned long long g_afl[BB * 4 * 8];  // coarse candidates {score, (t+1)<<16|bin<<8}
__device__ unsigned long long g_bfl[BB * 4 * 8];  // fine candidates

#define au(x) __float_as_uint(x)

// ---- pipelined coherent (L2-bypassing) loads/stores, no drains on stores ----
__device__ __forceinline__ void cload7x4(const float* p, f32x4& a0, f32x4& a1, f32x4& a2,
                                         f32x4& a3, f32x4& a4, f32x4& a5, f32x4& a6) {
  asm volatile(
      "global_load_dwordx4 %0, %7, off sc0 sc1\n\t"
      "global_load_dwordx4 %1, %7, off offset:16 sc0 sc1\n\t"
      "global_load_dwordx4 %2, %7, off offset:32 sc0 sc1\n\t"
      "global_load_dwordx4 %3, %7, off offset:48 sc0 sc1\n\t"
      "global_load_dwordx4 %4, %7, off offset:64 sc0 sc1\n\t"
      "global_load_dwordx4 %5, %7, off offset:80 sc0 sc1\n\t"
      "global_load_dwordx4 %6, %7, off offset:96 sc0 sc1\n\t"
      "s_waitcnt vmcnt(0)"
      : "=&v"(a0), "=&v"(a1), "=&v"(a2), "=&v"(a3), "=&v"(a4), "=&v"(a5), "=&v"(a6)
      : "v"(p) : "memory");
}
__device__ __forceinline__ void cload2x4(const float* p, f32x4& a, f32x4& b) {
  asm volatile(
      "global_load_dwordx4 %0, %2, off sc0 sc1\n\t"
      "global_load_dwordx4 %1, %2, off offset:16 sc0 sc1\n\t"
      "s_waitcnt vmcnt(0)"
      : "=&v"(a), "=&v"(b) : "v"(p) : "memory");
}
__device__ __forceinline__ void cstore4f_nw(float* p, f32x4 v) {
  asm volatile("global_store_dwordx4 %0, %1, off sc0 sc1" :: "v"(p), "v"(v) : "memory");
}
__device__ __forceinline__ void cstore2f_nw(float* p, f32x2 v) {
  asm volatile("global_store_dwordx2 %0, %1, off sc0 sc1" :: "v"(p), "v"(v) : "memory");
}
__device__ __forceinline__ void cstore2u_nw(unsigned long long* p, f32x2 v) {
  asm volatile("global_store_dwordx2 %0, %1, off sc0 sc1" :: "v"(p), "v"(v) : "memory");
}
__device__ __forceinline__ unsigned long long waitFlag64(unsigned long long* f, uint32_t tag) {
  unsigned long long u;
  while ((uint32_t)((u = __hip_atomic_load(f, __ATOMIC_RELAXED, __HIP_MEMORY_SCOPE_AGENT)) >> 48) < tag)
    __builtin_amdgcn_s_sleep(1);
  return u;
}

__device__ __forceinline__ uint32_t rotl32(uint32_t v, int d) {
  return (v << d) | (v >> (32 - d));
}

// JAX threefry2x32 (20 rounds), bit-exact
__device__ __forceinline__ uint2 tf2(uint32_t k0, uint32_t k1, uint32_t x0, uint32_t x1) {
  const uint32_t k2 = k0 ^ k1 ^ 0x1BD11BDAu;
  x0 += k0; x1 += k1;
  x0 += x1; x1 = rotl32(x1,13); x1 ^= x0;
  x0 += x1; x1 = rotl32(x1,15); x1 ^= x0;
  x0 += x1; x1 = rotl32(x1,26); x1 ^= x0;
  x0 += x1; x1 = rotl32(x1, 6); x1 ^= x0;
  x0 += k1; x1 += k2 + 1u;
  x0 += x1; x1 = rotl32(x1,17); x1 ^= x0;
  x0 += x1; x1 = rotl32(x1,29); x1 ^= x0;
  x0 += x1; x1 = rotl32(x1,16); x1 ^= x0;
  x0 += x1; x1 = rotl32(x1,24); x1 ^= x0;
  x0 += k2; x1 += k0 + 2u;
  x0 += x1; x1 = rotl32(x1,13); x1 ^= x0;
  x0 += x1; x1 = rotl32(x1,15); x1 ^= x0;
  x0 += x1; x1 = rotl32(x1,26); x1 ^= x0;
  x0 += x1; x1 = rotl32(x1, 6); x1 ^= x0;
  x0 += k0; x1 += k1 + 3u;
  x0 += x1; x1 = rotl32(x1,17); x1 ^= x0;
  x0 += x1; x1 = rotl32(x1,29); x1 ^= x0;
  x0 += x1; x1 = rotl32(x1,16); x1 ^= x0;
  x0 += x1; x1 = rotl32(x1,24); x1 ^= x0;
  x0 += k1; x1 += k2 + 4u;
  x0 += x1; x1 = rotl32(x1,13); x1 ^= x0;
  x0 += x1; x1 = rotl32(x1,15); x1 ^= x0;
  x0 += x1; x1 = rotl32(x1,26); x1 ^= x0;
  x0 += x1; x1 = rotl32(x1, 6); x1 ^= x0;
  x0 += k2; x1 += k0 + 5u;
  return make_uint2(x0, x1);
}

__device__ __forceinline__ float gumbel_bits(uint32_t bits) {
  const float tiny = 1.17549435e-38f;
  float f = __uint_as_float((bits >> 9) | 0x3f800000u) - 1.0f;
  float u = fmaxf(tiny, f + tiny);
  return -logf(-logf(u));
}

// 64-bin logit partials from LDS weight slice wlds[448][65]; bit-identical chain order.
__device__ __forceinline__ void logits64(const float* __restrict__ wlds,
                                         const float* __restrict__ vec,
                                         float* __restrict__ plds, int tid) {
  const int w = tid >> 6, lane = tid & 63;
  float a = 0.f;
  const float* wp = wlds + (56 * w) * 65 + lane;
  const float* cp = vec + 56 * w;
#pragma unroll 8
  for (int ii = 0; ii < 56; ++ii)
    a = fmaf(cp[ii], wp[ii * 65], a);
  plds[(w << 6) | lane] = a;
}

__global__ __launch_bounds__(512, 1) void wavernn_init() {
  const int idx = blockIdx.x * 512 + threadIdx.x;   // 112 x 512 = 57344
  g_hpc[idx] = 0.f;
  g_hpf[idx] = 0.f;
  if (idx < BB * HF * 2) { g_hc[idx] = 0.f; g_hf[idx] = 0.f; }
  if (idx < BB * 4 * 8) { g_afl[idx] = 0ull; g_bfl[idx] = 0ull; }
}

__global__ __launch_bounds__(512, 1) void wavernn_main(
    const float* __restrict__ cond, const float* __restrict__ gib,
    const float* __restrict__ W_h,  const float* __restrict__ b_h,
    const float* __restrict__ W_ci, const float* __restrict__ b_ci,
    const float* __restrict__ W_fi, const float* __restrict__ b_fi,
    const float* __restrict__ W_bc, const float* __restrict__ b_bc,
    const float* __restrict__ W_bf, const float* __restrict__ b_bf,
    float* __restrict__ out) {
  extern __shared__ float smem[];
  const int wg = blockIdx.x, tid = threadIdx.x;

  if (wg < NC) {
    // ================= compute role: pure matvec on tagged pairs =================
    float* hlds = smem;                       // [16][900]
    const int wave = tid >> 6, lane = tid & 63;
    const int l32 = lane >> 1, b2 = lane & 1;
    const int tp = wave >> 2;                 // 0=coarse rows, 1=fine rows
    const int chan = (wg << 2) | (wave & 3);  // 0..447
    const int rb = tp ? (HF + chan) : chan;
    float4 w[3][7];
    float brow[3];
#pragma unroll
    for (int r = 0; r < 3; ++r) {
      const int row = r * SZ + rb;
      brow[r] = b_h[row];
#pragma unroll
      for (int m = 0; m < 7; ++m)
        w[r][m] = *(const float4*)&W_h[(size_t)row * SZ + 4 * l32 + 128 * m];
    }
    // staging map: thread -> (batch, 14-value chunk)
    const int bat = tid >> 5, chk = tid & 31;
    const float* srcC = g_hc + ((size_t)bat * HF + chk * 14) * 2;
    const float* srcF = g_hf + ((size_t)bat * HF + chk * 14) * 2;
    float* dstC = hlds + bat * 900 + chk * 14;
    float* dstF = dstC + HF;

    for (int t = 0; t < TT; ++t) {
      const uint32_t tgh = au((float)t);   // h_{t-1} carries tag t
      f32x4 a0, a1, a2, a3, a4, a5, a6;
      // ---- poll+stage coarse half
      for (;;) {
        cload7x4(srcC, a0, a1, a2, a3, a4, a5, a6);
        if (au(a0.y) >= tgh && au(a0.w) >= tgh && au(a1.y) >= tgh && au(a1.w) >= tgh &&
            au(a2.y) >= tgh && au(a2.w) >= tgh && au(a3.y) >= tgh && au(a3.w) >= tgh &&
            au(a4.y) >= tgh && au(a4.w) >= tgh && au(a5.y) >= tgh && au(a5.w) >= tgh &&
            au(a6.y) >= tgh && au(a6.w) >= tgh) break;
        __builtin_amdgcn_s_sleep(1);
      }
      __syncthreads();
      dstC[0] = a0.x; dstC[1] = a0.z; dstC[2] = a1.x; dstC[3] = a1.z;
      dstC[4] = a2.x; dstC[5] = a2.z; dstC[6] = a3.x; dstC[7] = a3.z;
      dstC[8] = a4.x; dstC[9] = a4.z; dstC[10] = a5.x; dstC[11] = a5.z;
      dstC[12] = a6.x; dstC[13] = a6.z;
      __syncthreads();
      float acc[3][8];
#pragma unroll
      for (int r = 0; r < 3; ++r)
#pragma unroll
        for (int i = 0; i < 8; ++i) acc[r][i] = 0.f;
#pragma unroll
      for (int i = 0; i < 8; ++i) {
        const int b = b2 + 2 * i;
        const float* hb = hlds + b * 900 + 4 * l32;
        const float4 h0 = *(const float4*)(hb);
        const float4 h1 = *(const float4*)(hb + 128);
        const float4 h2 = *(const float4*)(hb + 256);
#pragma unroll
        for (int r = 0; r < 3; ++r) {
          float s = acc[r][i];
          s = fmaf(w[r][0].x, h0.x, s); s = fmaf(w[r][0].y, h0.y, s);
          s = fmaf(w[r][0].z, h0.z, s); s = fmaf(w[r][0].w, h0.w, s);
          s = fmaf(w[r][1].x, h1.x, s); s = fmaf(w[r][1].y, h1.y, s);
          s = fmaf(w[r][1].z, h1.z, s); s = fmaf(w[r][1].w, h1.w, s);
          s = fmaf(w[r][2].x, h2.x, s); s = fmaf(w[r][2].y, h2.y, s);
          s = fmaf(w[r][2].z, h2.z, s); s = fmaf(w[r][2].w, h2.w, s);
          acc[r][i] = s;
        }
        if (l32 < 16) {
          const float4 h3 = *(const float4*)(hb + 384);
#pragma unroll
          for (int r = 0; r < 3; ++r) {
            float s = acc[r][i];
            s = fmaf(w[r][3].x, h3.x, s); s = fmaf(w[r][3].y, h3.y, s);
            s = fmaf(w[r][3].z, h3.z, s); s = fmaf(w[r][3].w, h3.w, s);
            acc[r][i] = s;
          }
        }
      }
      // ---- poll+stage fine half (disjoint LDS region; no barrier before writes needed)
      for (;;) {
        cload7x4(srcF, a0, a1, a2, a3, a4, a5, a6);
        if (au(a0.y) >= tgh && au(a0.w) >= tgh && au(a1.y) >= tgh && au(a1.w) >= tgh &&
            au(a2.y) >= tgh && au(a2.w) >= tgh && au(a3.y) >= tgh && au(a3.w) >= tgh &&
            au(a4.y) >= tgh && au(a4.w) >= tgh && au(a5.y) >= tgh && au(a5.w) >= tgh &&
            au(a6.y) >= tgh && au(a6.w) >= tgh) break;
        __builtin_amdgcn_s_sleep(1);
      }
      dstF[0] = a0.x; dstF[1] = a0.z; dstF[2] = a1.x; dstF[3] = a1.z;
      dstF[4] = a2.x; dstF[5] = a2.z; dstF[6] = a3.x; dstF[7] = a3.z;
      dstF[8] = a4.x; dstF[9] = a4.z; dstF[10] = a5.x; dstF[11] = a5.z;
      dstF[12] = a6.x; dstF[13] = a6.z;
      __syncthreads();
#pragma unroll
      for (int i = 0; i < 8; ++i) {
        const int b = b2 + 2 * i;
        const float* hb = hlds + b * 900 + 4 * l32;
        if (l32 >= 16) {
          const float4 h3 = *(const float4*)(hb + 384);
#pragma unroll
          for (int r = 0; r < 3; ++r) {
            float s = acc[r][i];
            s = fmaf(w[r][3].x, h3.x, s); s = fmaf(w[r][3].y, h3.y, s);
            s = fmaf(w[r][3].z, h3.z, s); s = fmaf(w[r][3].w, h3.w, s);
            acc[r][i] = s;
          }
        }
        const float4 h4 = *(const float4*)(hb + 512);
        const float4 h5 = *(const float4*)(hb + 640);
        const float4 h6 = *(const float4*)(hb + 768);
#pragma unroll
        for (int r = 0; r < 3; ++r) {
          float s = acc[r][i];
          s = fmaf(w[r][4].x, h4.x, s); s = fmaf(w[r][4].y, h4.y, s);
          s = fmaf(w[r][4].z, h4.z, s); s = fmaf(w[r][4].w, h4.w, s);
          s = fmaf(w[r][5].x, h5.x, s); s = fmaf(w[r][5].y, h5.y, s);
          s = fmaf(w[r][5].z, h5.z, s); s = fmaf(w[r][5].w, h5.w, s);
          s = fmaf(w[r][6].x, h6.x, s); s = fmaf(w[r][6].y, h6.y, s);
          s = fmaf(w[r][6].z, h6.z, s); s = fmaf(w[r][6].w, h6.w, s);
          acc[r][i] = s;
        }
      }
#pragma unroll
      for (int r = 0; r < 3; ++r)
#pragma unroll
        for (int i = 0; i < 8; ++i) {
          float v = acc[r][i];
          v += __shfl_xor(v, 2);
          v += __shfl_xor(v, 4);
          v += __shfl_xor(v, 8);
          v += __shfl_xor(v, 16);
          v += __shfl_xor(v, 32);
          acc[r][i] = v;
        }
      // ---- publish hp rows as tagged pairs; no drain, no flag
      if (lane < 16) {
        const int bb = lane, i = lane >> 1;
        const float tgf = (float)(t + 1);
        f32x4 q; q.x = acc[0][i] + brow[0]; q.y = tgf; q.z = acc[1][i] + brow[1]; q.w = tgf;
        f32x2 r2; r2.x = acc[2][i] + brow[2]; r2.y = tgf;
        float* dst = (tp ? g_hpf : g_hpc) + ((size_t)bb * HF + chan) * 8;
        cstore4f_nw(dst, q);
        cstore2f_nw(dst + 4, r2);
      }
    }
  } else {
    // ================= sampler role: 4 coarse + 4 fine WGs per batch =================
    const int swg = wg - NC;            // 0..127
    const int b = swg >> 3;
    const int role = (swg >> 2) & 1;    // 0 = coarse, 1 = fine
    const int k = swg & 3;              // 64-bin slice
    float* wlds = smem;                 // [448][65]
    float* vlds = smem + 29120;         // [448] state (ch or fh)
    float* plds = smem + 29568;         // [8][64]
    float* aS = smem + 30080;           // [4]
    int*   aI = (int*)(smem + 30084);
    float* bS = smem + 30088;
    int*   bI = (int*)(smem + 30092);
    {
      const float* Wm = role ? W_bf : W_bc;
      for (int i = tid; i < HF * 64; i += 512) {
        const int bn = i / HF, kk = i - bn * HF;
        wlds[kk * 65 + bn] = Wm[(size_t)(64 * k + bn) * HF + kk];
      }
    }
    const float* bias = role ? b_bf : b_bc;
    float gw0[3], gw1[3], gw2[3], gbe[3], pc[3];
    if (tid < HF) {
      if (role == 0) {
#pragma unroll
        for (int g = 0; g < 3; ++g) {
          const int rr = g * HF + tid;
          gw0[g] = W_ci[2 * rr]; gw1[g] = W_ci[2 * rr + 1]; gw2[g] = 0.f;
          gbe[g] = b_ci[rr] + gib[g * SZ + tid];
          pc[g] = cond[(((size_t)b * TT) * 3 + g) * SZ + tid];
        }
      } else {
#pragma unroll
        for (int g = 0; g < 3; ++g) {
          const int rr = g * HF + tid;
          gw0[g] = W_fi[3 * rr]; gw1[g] = W_fi[3 * rr + 1]; gw2[g] = W_fi[3 * rr + 2];
          gbe[g] = b_fi[rr] + gib[g * SZ + HF + tid];
          pc[g] = cond[(((size_t)b * TT) * 3 + g) * SZ + HF + tid];
        }
      }
      vlds[tid] = 0.f;
    }
    __syncthreads();
    float cvO = -1.f, fvO = -1.f;
    const float* hpSrc = (role ? g_hpf : g_hpc) + ((size_t)b * HF + (tid < HF ? tid : 0)) * 8;

    for (int t = 0; t < TT; ++t) {
      const uint2 kf = tf2(0u, 1u, 0u, (uint32_t)t);
      float gub = 0.f;
      if (tid < 64) {
        const uint2 kk = role ? tf2(kf.x, kf.y, 0u, 1u) : tf2(kf.x, kf.y, 0u, 0u);
        const uint2 o = tf2(kk.x, kk.y, 0u, (uint32_t)(b * 256 + 64 * k + tid));
        gub = gumbel_bits(o.x ^ o.y);
      }
      const uint32_t tgp = au((float)(t + 1));
      f32x4 h0, h1;
      if (tid < HF) {   // poll own hp row (tag t+1)
        for (;;) {
          cload2x4(hpSrc, h0, h1);
          if (au(h0.y) >= tgp && au(h0.w) >= tgp && au(h1.y) >= tgp) break;
          __builtin_amdgcn_s_sleep(1);
        }
      }
      if (role == 0) {
        // ------- coarse WG: gates -> publish ch -> logits -> afl -------
        if (t > 0 && tid >= 452 && tid < 456) {
          const unsigned long long u = waitFlag64(&g_bfl[(b * 4 + (tid - 452)) * 8], (uint32_t)t);
          bS[tid - 452] = __uint_as_float((uint32_t)u);
          bI[tid - 452] = (int)((u >> 40) & 255u);
        }
        __syncthreads();
        float fvv = -1.f;
        if (t > 0) {
          float ms = bS[0]; int sf = bI[0];
#pragma unroll
          for (int m = 1; m < 4; ++m) {
            const float so = bS[m]; const int io = bI[m];
            if (so > ms || (so == ms && io < sf)) { ms = so; sf = io; }
          }
          fvv = (float)sf / 127.5f - 1.0f;
        }
        if (tid < HF) {
          const float cp0 = fmaf(cvO, gw0[0], fmaf(fvv, gw1[0], gbe[0])) + pc[0];
          const float cp1 = fmaf(cvO, gw0[1], fmaf(fvv, gw1[1], gbe[1])) + pc[1];
          const float cp2 = fmaf(cvO, gw0[2], fmaf(fvv, gw1[2], gbe[2])) + pc[2];
          const float rg = 1.f / (1.f + expf(-(cp0 + h0.x)));
          const float ug = 1.f / (1.f + expf(-(cp1 + h0.z)));
          const float eg = tanhf(fmaf(rg, h1.x, cp2));
          vlds[tid] = ug * vlds[tid] + (1.f - ug) * eg;
        }
        __syncthreads();
        if (tid < 112) {   // publish own quarter of ch_t as tagged pairs
          const int pos = 112 * k + tid;
          f32x2 pv; pv.x = vlds[pos]; pv.y = (float)(t + 1);
          cstore2f_nw(g_hc + ((size_t)b * HF + pos) * 2, pv);
        }
        logits64(wlds, vlds, plds, tid);
        __syncthreads();
        if (tid < 64) {
          const float p0 = plds[tid],       p1 = plds[64 + tid];
          const float p2 = plds[128 + tid], p3 = plds[192 + tid];
          const float p4 = plds[256 + tid], p5 = plds[320 + tid];
          const float p6 = plds[384 + tid], p7 = plds[448 + tid];
          const float sum = ((p0 + p1) + (p2 + p3)) + ((p4 + p5) + (p6 + p7));
          float s = (sum + bias[64 * k + tid]) + gub;
          int idx = 64 * k + tid;
#pragma unroll
          for (int m = 1; m < 64; m <<= 1) {
            const float so = __shfl_xor(s, m);
            const int io = __shfl_xor(idx, m);
            if (so > s || (so == s && io < idx)) { s = so; idx = io; }
          }
          if (tid == 0) {
            f32x2 v; v.x = s;
            v.y = __uint_as_float(((uint32_t)(t + 1) << 16) | ((uint32_t)idx << 8));
            cstore2u_nw(&g_afl[(b * 4 + k) * 8], v);
          }
        }
        if (tid >= 448 && tid < 452) {
          const unsigned long long u = waitFlag64(&g_afl[(b * 4 + (tid - 448)) * 8], (uint32_t)(t + 1));
          aS[tid - 448] = __uint_as_float((uint32_t)u);
          aI[tid - 448] = (int)((u >> 40) & 255u);
        }
        __syncthreads();
        {
          float ms = aS[0]; int sc = aI[0];
#pragma unroll
          for (int m = 1; m < 4; ++m) {
            const float so = aS[m]; const int io = aI[m];
            if (so > ms || (so == ms && io < sc)) { ms = so; sc = io; }
          }
          cvO = (float)sc / 127.5f - 1.0f;
          if (k == 0 && tid == 0) out[b * TT + t] = (float)sc;
        }
        if (tid < HF && t + 1 < TT) {
#pragma unroll
          for (int g = 0; g < 3; ++g)
            pc[g] = cond[(((size_t)b * TT + (t + 1)) * 3 + g) * SZ + tid];
        }
      } else {
        // ------- fine WG: sc -> gates -> publish fh -> logits -> bfl -------
        if (tid >= 448 && tid < 452) {
          const unsigned long long u = waitFlag64(&g_afl[(b * 4 + (tid - 448)) * 8], (uint32_t)(t + 1));
          aS[tid - 448] = __uint_as_float((uint32_t)u);
          aI[tid - 448] = (int)((u >> 40) & 255u);
        }
        __syncthreads();
        float ms = aS[0]; int sc = aI[0];
#pragma unroll
        for (int m = 1; m < 4; ++m) {
          const float so = aS[m]; const int io = aI[m];
          if (so > ms || (so == ms && io < sc)) { ms = so; sc = io; }
        }
        const float cvNew = (float)sc / 127.5f - 1.0f;
        if (tid < HF) {
          const float fp0 = fmaf(cvO, gw0[0], fmaf(fvO, gw1[0], fmaf(cvNew, gw2[0], gbe[0]))) + pc[0];
          const float fp1 = fmaf(cvO, gw0[1], fmaf(fvO, gw1[1], fmaf(cvNew, gw2[1], gbe[1]))) + pc[1];
          const float fp2 = fmaf(cvO, gw0[2], fmaf(fvO, gw1[2], fmaf(cvNew, gw2[2], gbe[2]))) + pc[2];
          const float rg = 1.f / (1.f + expf(-(fp0 + h0.x)));
          const float ug = 1.f / (1.f + expf(-(fp1 + h0.z)));
          const float eg = tanhf(fmaf(rg, h1.x, fp2));
          vlds[tid] = ug * vlds[tid] + (1.f - ug) * eg;
        }
        __syncthreads();
        if (tid < 112) {   // publish own quarter of fh_t as tagged pairs
          const int pos = 112 * k + tid;
          f32x2 pv; pv.x = vlds[pos]; pv.y = (float)(t + 1);
          cstore2f_nw(g_hf + ((size_t)b * HF + pos) * 2, pv);
        }
        logits64(wlds, vlds, plds, tid);
        __syncthreads();
        if (tid < 64) {
          const float p0 = plds[tid],       p1 = plds[64 + tid];
          const float p2 = plds[128 + tid], p3 = plds[192 + tid];
          const float p4 = plds[256 + tid], p5 = plds[320 + tid];
          const float p6 = plds[384 + tid], p7 = plds[448 + tid];
          const float sum = ((p0 + p1) + (p2 + p3)) + ((p4 + p5) + (p6 + p7));
          float s = (sum + bias[64 * k + tid]) + gub;
          int idx = 64 * k + tid;
#pragma unroll
          for (int m = 1; m < 64; m <<= 1) {
            const float so = __shfl_xor(s, m);
            const int io = __shfl_xor(idx, m);
            if (so > s || (so == s && io < idx)) { s = so; idx = io; }
          }
          if (tid == 0) {
            f32x2 v; v.x = s;
            v.y = __uint_as_float(((uint32_t)(t + 1) << 16) | ((uint32_t)idx << 8));
            cstore2u_nw(&g_bfl[(b * 4 + k) * 8], v);
          }
        }
        if (tid >= 448 && tid < 452) {
          const unsigned long long u = waitFlag64(&g_bfl[(b * 4 + (tid - 448)) * 8], (uint32_t)(t + 1));
          bS[tid - 448] = __uint_as_float((uint32_t)u);
          bI[tid - 448] = (int)((u >> 40) & 255u);
        }
        __syncthreads();
        {
          float msf = bS[0]; int sf = bI[0];
#pragma unroll
          for (int m = 1; m < 4; ++m) {
            const float so = bS[m]; const int io = bI[m];
            if (so > msf || (so == msf && io < sf)) { msf = so; sf = io; }
          }
          fvO = (float)sf / 127.5f - 1.0f;
          if (k == 0 && tid == 0) out[BB * TT + b * TT + t] = (float)sf;
        }
        cvO = cvNew;
        if (tid < HF && t + 1 < TT) {
#pragma unroll
          for (int g = 0; g < 3; ++g)
            pc[g] = cond[(((size_t)b * TT + (t + 1)) * 3 + g) * SZ + HF + tid];
        }
      }
    }
    // final hidden from LDS state
    if (k == 0 && tid < HF) {
      if (role == 0) out[2 * BB * TT + (size_t)b * SZ + tid] = vlds[tid];
      else           out[2 * BB * TT + (size_t)b * SZ + HF + tid] = vlds[tid];
    }
  }
}

extern "C" void kernel_launch(void* const* d_in, const int* in_sizes, int n_in,
                              void* d_out, int out_size, void* d_ws, size_t ws_size,
                              hipStream_t stream) {
  (void)in_sizes; (void)n_in; (void)out_size; (void)d_ws; (void)ws_size;
  const float* cond = (const float*)d_in[0];
  const float* gib  = (const float*)d_in[1];
  const float* W_h  = (const float*)d_in[2];
  const float* b_h  = (const float*)d_in[3];
  const float* W_ci = (const float*)d_in[4];
  const float* b_ci = (const float*)d_in[5];
  const float* W_fi = (const float*)d_in[6];
  const float* b_fi = (const float*)d_in[7];
  const float* W_bc = (const float*)d_in[8];
  const float* b_bc = (const float*)d_in[9];
  const float* W_bf = (const float*)d_in[10];
  const float* b_bf = (const float*)d_in[11];
  float* out = (float*)d_out;
  hipFuncSetAttribute((const void*)wavernn_main,
                      hipFuncAttributeMaxDynamicSharedMemorySize, LDS_BYTES);
  wavernn_init<<<NC, 512, 0, stream>>>();
  wavernn_main<<<NWG, 512, LDS_BYTES, stream>>>(cond, gib, W_h, b_h, W_ci, b_ci,
                                                W_fi, b_fi, W_bc, b_bc, W_bf, b_bf, out);
}

// Round 9
// 14232.449 us; speedup vs baseline: 1.4265x; 1.4265x over previous
//
#include <hip/hip_runtime.h>
#include <stdint.h>

#define BB 16
#define TT 1000
#define SZ 896
#define HF 448
#define NC 112            // compute WGs (pure matvec)
#define NWG 240           // 112 compute + 128 sampler (16 x (4 coarse + 4 fine))
#define LDS_FLOATS 30112
#define LDS_BYTES (LDS_FLOATS * 4)

typedef float f32x4 __attribute__((ext_vector_type(4)));
typedef float f32x2 __attribute__((ext_vector_type(2)));

// Persistent device-global state. Cross-WG data = (value, tag) pairs; tag = float(t+1).
__device__ float g_hc[BB * HF * 2];      // coarse hidden pairs [16][448][2]
__device__ float g_hf[BB * HF * 2];      // fine hidden pairs
__device__ float g_hpc[BB * HF * 8];     // coarse hp rows [16][448][{s0,t,s1,t,s2,t,p,p}]
__device__ float g_hpf[BB * HF * 8];     // fine hp rows
__device__ uint32_t g_cdone[NC * 16];    // C-WG hp issued: value = t+1
__device__ uint32_t g_chrdy[BB * 16];    // ch_t pairs issued
__device__ uint32_t g_fhrdy[BB * 16];    // fh_t pairs issued
__device__ unsigned long long g_afl[BB * 4 * 8];  // coarse candidates {score, (t+1)<<16|bin<<8}
__device__ unsigned long long g_bfl[BB * 4 * 8];  // fine candidates

#define au(x) __float_as_uint(x)

// ---- pipelined coherent (L2-bypassing) accesses ----
__device__ __forceinline__ void cload7x4(const float* p, f32x4& a0, f32x4& a1, f32x4& a2,
                                         f32x4& a3, f32x4& a4, f32x4& a5, f32x4& a6) {
  asm volatile(
      "global_load_dwordx4 %0, %7, off sc0 sc1\n\t"
      "global_load_dwordx4 %1, %7, off offset:16 sc0 sc1\n\t"
      "global_load_dwordx4 %2, %7, off offset:32 sc0 sc1\n\t"
      "global_load_dwordx4 %3, %7, off offset:48 sc0 sc1\n\t"
      "global_load_dwordx4 %4, %7, off offset:64 sc0 sc1\n\t"
      "global_load_dwordx4 %5, %7, off offset:80 sc0 sc1\n\t"
      "global_load_dwordx4 %6, %7, off offset:96 sc0 sc1\n\t"
      "s_waitcnt vmcnt(0)"
      : "=&v"(a0), "=&v"(a1), "=&v"(a2), "=&v"(a3), "=&v"(a4), "=&v"(a5), "=&v"(a6)
      : "v"(p) : "memory");
}
__device__ __forceinline__ void cload2x4(const float* p, f32x4& a, f32x4& b) {
  asm volatile(
      "global_load_dwordx4 %0, %2, off sc0 sc1\n\t"
      "global_load_dwordx4 %1, %2, off offset:16 sc0 sc1\n\t"
      "s_waitcnt vmcnt(0)"
      : "=&v"(a), "=&v"(b) : "v"(p) : "memory");
}
__device__ __forceinline__ void cstore4f_nw(float* p, f32x4 v) {
  asm volatile("global_store_dwordx4 %0, %1, off sc0 sc1" :: "v"(p), "v"(v) : "memory");
}
__device__ __forceinline__ void cstore2f_nw(float* p, f32x2 v) {
  asm volatile("global_store_dwordx2 %0, %1, off sc0 sc1" :: "v"(p), "v"(v) : "memory");
}
__device__ __forceinline__ void cstore1u_nw(uint32_t* p, uint32_t v) {
  asm volatile("global_store_dword %0, %1, off sc0 sc1" :: "v"(p), "v"(v) : "memory");
}
__device__ __forceinline__ void cstore2u_nw(unsigned long long* p, f32x2 v) {
  asm volatile("global_store_dwordx2 %0, %1, off sc0 sc1" :: "v"(p), "v"(v) : "memory");
}
__device__ __forceinline__ void waitFlag(uint32_t* f, uint32_t target) {
  while (__hip_atomic_load(f, __ATOMIC_RELAXED, __HIP_MEMORY_SCOPE_AGENT) < target)
    __builtin_amdgcn_s_sleep(1);
}
__device__ __forceinline__ void waitFlagA(uint32_t* f, uint32_t target) {
  while (__hip_atomic_load(f, __ATOMIC_RELAXED, __HIP_MEMORY_SCOPE_AGENT) < target)
    __builtin_amdgcn_s_sleep(2);
}
__device__ __forceinline__ unsigned long long waitFlag64(unsigned long long* f, uint32_t tag) {
  unsigned long long u;
  while ((uint32_t)((u = __hip_atomic_load(f, __ATOMIC_RELAXED, __HIP_MEMORY_SCOPE_AGENT)) >> 48) < tag)
    __builtin_amdgcn_s_sleep(1);
  return u;
}

__device__ __forceinline__ uint32_t rotl32(uint32_t v, int d) {
  return (v << d) | (v >> (32 - d));
}

// JAX threefry2x32 (20 rounds), bit-exact
__device__ __forceinline__ uint2 tf2(uint32_t k0, uint32_t k1, uint32_t x0, uint32_t x1) {
  const uint32_t k2 = k0 ^ k1 ^ 0x1BD11BDAu;
  x0 += k0; x1 += k1;
  x0 += x1; x1 = rotl32(x1,13); x1 ^= x0;
  x0 += x1; x1 = rotl32(x1,15); x1 ^= x0;
  x0 += x1; x1 = rotl32(x1,26); x1 ^= x0;
  x0 += x1; x1 = rotl32(x1, 6); x1 ^= x0;
  x0 += k1; x1 += k2 + 1u;
  x0 += x1; x1 = rotl32(x1,17); x1 ^= x0;
  x0 += x1; x1 = rotl32(x1,29); x1 ^= x0;
  x0 += x1; x1 = rotl32(x1,16); x1 ^= x0;
  x0 += x1; x1 = rotl32(x1,24); x1 ^= x0;
  x0 += k2; x1 += k0 + 2u;
  x0 += x1; x1 = rotl32(x1,13); x1 ^= x0;
  x0 += x1; x1 = rotl32(x1,15); x1 ^= x0;
  x0 += x1; x1 = rotl32(x1,26); x1 ^= x0;
  x0 += x1; x1 = rotl32(x1, 6); x1 ^= x0;
  x0 += k0; x1 += k1 + 3u;
  x0 += x1; x1 = rotl32(x1,17); x1 ^= x0;
  x0 += x1; x1 = rotl32(x1,29); x1 ^= x0;
  x0 += x1; x1 = rotl32(x1,16); x1 ^= x0;
  x0 += x1; x1 = rotl32(x1,24); x1 ^= x0;
  x0 += k1; x1 += k2 + 4u;
  x0 += x1; x1 = rotl32(x1,13); x1 ^= x0;
  x0 += x1; x1 = rotl32(x1,15); x1 ^= x0;
  x0 += x1; x1 = rotl32(x1,26); x1 ^= x0;
  x0 += x1; x1 = rotl32(x1, 6); x1 ^= x0;
  x0 += k2; x1 += k0 + 5u;
  return make_uint2(x0, x1);
}

__device__ __forceinline__ float gumbel_bits(uint32_t bits) {
  const float tiny = 1.17549435e-38f;
  float f = __uint_as_float((bits >> 9) | 0x3f800000u) - 1.0f;
  float u = fmaxf(tiny, f + tiny);
  return -logf(-logf(u));
}

// 64-bin logit partials from LDS weight slice wlds[448][65]; bit-identical chain order.
__device__ __forceinline__ void logits64(const float* __restrict__ wlds,
                                         const float* __restrict__ vec,
                                         float* __restrict__ plds, int tid) {
  const int w = tid >> 6, lane = tid & 63;
  float a = 0.f;
  const float* wp = wlds + (56 * w) * 65 + lane;
  const float* cp = vec + 56 * w;
#pragma unroll 8
  for (int ii = 0; ii < 56; ++ii)
    a = fmaf(cp[ii], wp[ii * 65], a);
  plds[(w << 6) | lane] = a;
}

__global__ __launch_bounds__(512, 1) void wavernn_init() {
  const int idx = blockIdx.x * 512 + threadIdx.x;   // 112 x 512 = 57344
  g_hpc[idx] = 0.f;
  g_hpf[idx] = 0.f;
  if (idx < BB * HF * 2) { g_hc[idx] = 0.f; g_hf[idx] = 0.f; }
  if (idx < NC * 16) g_cdone[idx] = 0u;
  if (idx < BB * 16) { g_chrdy[idx] = 0u; g_fhrdy[idx] = 0u; }
  if (idx < BB * 4 * 8) { g_afl[idx] = 0ull; g_bfl[idx] = 0ull; }
}

__global__ __launch_bounds__(512, 1) void wavernn_main(
    const float* __restrict__ cond, const float* __restrict__ gib,
    const float* __restrict__ W_h,  const float* __restrict__ b_h,
    const float* __restrict__ W_ci, const float* __restrict__ b_ci,
    const float* __restrict__ W_fi, const float* __restrict__ b_fi,
    const float* __restrict__ W_bc, const float* __restrict__ b_bc,
    const float* __restrict__ W_bf, const float* __restrict__ b_bf,
    float* __restrict__ out) {
  extern __shared__ float smem[];
  const int wg = blockIdx.x, tid = threadIdx.x;

  if (wg < NC) {
    // ================= compute role: pure matvec =================
    float* hlds = smem;                       // [16][900]
    const int wave = tid >> 6, lane = tid & 63;
    const int l32 = lane >> 1, b2 = lane & 1;
    const int tp = wave >> 2;                 // 0=coarse rows, 1=fine rows
    const int chan = (wg << 2) | (wave & 3);  // 0..447
    const int rb = tp ? (HF + chan) : chan;
    float4 w[3][7];
    float brow[3];
#pragma unroll
    for (int r = 0; r < 3; ++r) {
      const int row = r * SZ + rb;
      brow[r] = b_h[row];
#pragma unroll
      for (int m = 0; m < 7; ++m)
        w[r][m] = *(const float4*)&W_h[(size_t)row * SZ + 4 * l32 + 128 * m];
    }
    // staging map: thread -> (batch, 14-pair chunk)
    const int bat = tid >> 5, chk = tid & 31;
    const float* srcC = g_hc + ((size_t)bat * HF + chk * 14) * 2;
    const float* srcF = g_hf + ((size_t)bat * HF + chk * 14) * 2;
    float* dstC = hlds + bat * 900 + chk * 14;
    float* dstF = dstC + HF;

    for (int t = 0; t < TT; ++t) {
      const uint32_t tgh = au((float)t);   // h_{t-1} tag
      f32x4 a0, a1, a2, a3, a4, a5, a6;
      // ---- narrow flag poll (long idle lives here), then one wide verified load
      if (tid < BB) waitFlagA(&g_chrdy[tid * 16], (uint32_t)t);
      __syncthreads();
      for (;;) {
        cload7x4(srcC, a0, a1, a2, a3, a4, a5, a6);
        if (au(a0.y) >= tgh && au(a0.w) >= tgh && au(a1.y) >= tgh && au(a1.w) >= tgh &&
            au(a2.y) >= tgh && au(a2.w) >= tgh && au(a3.y) >= tgh && au(a3.w) >= tgh &&
            au(a4.y) >= tgh && au(a4.w) >= tgh && au(a5.y) >= tgh && au(a5.w) >= tgh &&
            au(a6.y) >= tgh && au(a6.w) >= tgh) break;
        __builtin_amdgcn_s_sleep(1);
      }
      dstC[0] = a0.x; dstC[1] = a0.z; dstC[2] = a1.x; dstC[3] = a1.z;
      dstC[4] = a2.x; dstC[5] = a2.z; dstC[6] = a3.x; dstC[7] = a3.z;
      dstC[8] = a4.x; dstC[9] = a4.z; dstC[10] = a5.x; dstC[11] = a5.z;
      dstC[12] = a6.x; dstC[13] = a6.z;
      __syncthreads();
      float acc[3][8];
#pragma unroll
      for (int r = 0; r < 3; ++r)
#pragma unroll
        for (int i = 0; i < 8; ++i) acc[r][i] = 0.f;
#pragma unroll
      for (int i = 0; i < 8; ++i) {
        const int b = b2 + 2 * i;
        const float* hb = hlds + b * 900 + 4 * l32;
        const float4 h0 = *(const float4*)(hb);
        const float4 h1 = *(const float4*)(hb + 128);
        const float4 h2 = *(const float4*)(hb + 256);
#pragma unroll
        for (int r = 0; r < 3; ++r) {
          float s = acc[r][i];
          s = fmaf(w[r][0].x, h0.x, s); s = fmaf(w[r][0].y, h0.y, s);
          s = fmaf(w[r][0].z, h0.z, s); s = fmaf(w[r][0].w, h0.w, s);
          s = fmaf(w[r][1].x, h1.x, s); s = fmaf(w[r][1].y, h1.y, s);
          s = fmaf(w[r][1].z, h1.z, s); s = fmaf(w[r][1].w, h1.w, s);
          s = fmaf(w[r][2].x, h2.x, s); s = fmaf(w[r][2].y, h2.y, s);
          s = fmaf(w[r][2].z, h2.z, s); s = fmaf(w[r][2].w, h2.w, s);
          acc[r][i] = s;
        }
        if (l32 < 16) {
          const float4 h3 = *(const float4*)(hb + 384);
#pragma unroll
          for (int r = 0; r < 3; ++r) {
            float s = acc[r][i];
            s = fmaf(w[r][3].x, h3.x, s); s = fmaf(w[r][3].y, h3.y, s);
            s = fmaf(w[r][3].z, h3.z, s); s = fmaf(w[r][3].w, h3.w, s);
            acc[r][i] = s;
          }
        }
      }
      // ---- fine half: narrow flag poll, then wide verified load
      if (tid < BB) waitFlag(&g_fhrdy[tid * 16], (uint32_t)t);
      __syncthreads();
      for (;;) {
        cload7x4(srcF, a0, a1, a2, a3, a4, a5, a6);
        if (au(a0.y) >= tgh && au(a0.w) >= tgh && au(a1.y) >= tgh && au(a1.w) >= tgh &&
            au(a2.y) >= tgh && au(a2.w) >= tgh && au(a3.y) >= tgh && au(a3.w) >= tgh &&
            au(a4.y) >= tgh && au(a4.w) >= tgh && au(a5.y) >= tgh && au(a5.w) >= tgh &&
            au(a6.y) >= tgh && au(a6.w) >= tgh) break;
        __builtin_amdgcn_s_sleep(1);
      }
      dstF[0] = a0.x; dstF[1] = a0.z; dstF[2] = a1.x; dstF[3] = a1.z;
      dstF[4] = a2.x; dstF[5] = a2.z; dstF[6] = a3.x; dstF[7] = a3.z;
      dstF[8] = a4.x; dstF[9] = a4.z; dstF[10] = a5.x; dstF[11] = a5.z;
      dstF[12] = a6.x; dstF[13] = a6.z;
      __syncthreads();
#pragma unroll
      for (int i = 0; i < 8; ++i) {
        const int b = b2 + 2 * i;
        const float* hb = hlds + b * 900 + 4 * l32;
        if (l32 >= 16) {
          const float4 h3 = *(const float4*)(hb + 384);
#pragma unroll
          for (int r = 0; r < 3; ++r) {
            float s = acc[r][i];
            s = fmaf(w[r][3].x, h3.x, s); s = fmaf(w[r][3].y, h3.y, s);
            s = fmaf(w[r][3].z, h3.z, s); s = fmaf(w[r][3].w, h3.w, s);
            acc[r][i] = s;
          }
        }
        const float4 h4 = *(const float4*)(hb + 512);
        const float4 h5 = *(const float4*)(hb + 640);
        const float4 h6 = *(const float4*)(hb + 768);
#pragma unroll
        for (int r = 0; r < 3; ++r) {
          float s = acc[r][i];
          s = fmaf(w[r][4].x, h4.x, s); s = fmaf(w[r][4].y, h4.y, s);
          s = fmaf(w[r][4].z, h4.z, s); s = fmaf(w[r][4].w, h4.w, s);
          s = fmaf(w[r][5].x, h5.x, s); s = fmaf(w[r][5].y, h5.y, s);
          s = fmaf(w[r][5].z, h5.z, s); s = fmaf(w[r][5].w, h5.w, s);
          s = fmaf(w[r][6].x, h6.x, s); s = fmaf(w[r][6].y, h6.y, s);
          s = fmaf(w[r][6].z, h6.z, s); s = fmaf(w[r][6].w, h6.w, s);
          acc[r][i] = s;
        }
      }
#pragma unroll
      for (int r = 0; r < 3; ++r)
#pragma unroll
        for (int i = 0; i < 8; ++i) {
          float v = acc[r][i];
          v += __shfl_xor(v, 2);
          v += __shfl_xor(v, 4);
          v += __shfl_xor(v, 8);
          v += __shfl_xor(v, 16);
          v += __shfl_xor(v, 32);
          acc[r][i] = v;
        }
      // ---- publish tagged hp rows; raw barrier (no drain) orders issue; then flag
      if (lane < 16) {
        const int bb = lane, i = lane >> 1;
        const float tgf = (float)(t + 1);
        f32x4 q; q.x = acc[0][i] + brow[0]; q.y = tgf; q.z = acc[1][i] + brow[1]; q.w = tgf;
        f32x2 r2; r2.x = acc[2][i] + brow[2]; r2.y = tgf;
        float* dst = (tp ? g_hpf : g_hpc) + ((size_t)bb * HF + chan) * 8;
        cstore4f_nw(dst, q);
        cstore2f_nw(dst + 4, r2);
      }
      __builtin_amdgcn_s_barrier();
      if (tid == 0) cstore1u_nw(&g_cdone[wg * 16], (uint32_t)(t + 1));
    }
  } else {
    // ================= sampler role: 4 coarse + 4 fine WGs per batch =================
    const int swg = wg - NC;            // 0..127
    const int b = swg >> 3;
    const int role = (swg >> 2) & 1;    // 0 = coarse, 1 = fine
    const int k = swg & 3;              // 64-bin slice
    float* wlds = smem;                 // [448][65]
    float* vlds = smem + 29120;         // [448] state (ch or fh)
    float* plds = smem + 29568;         // [8][64]
    float* aS = smem + 30080;           // [4]
    int*   aI = (int*)(smem + 30084);
    float* bS = smem + 30088;
    int*   bI = (int*)(smem + 30092);
    {
      const float* Wm = role ? W_bf : W_bc;
      for (int i = tid; i < HF * 64; i += 512) {
        const int bn = i / HF, kk = i - bn * HF;
        wlds[kk * 65 + bn] = Wm[(size_t)(64 * k + bn) * HF + kk];
      }
    }
    const float* bias = role ? b_bf : b_bc;
    float gw0[3], gw1[3], gw2[3], gbe[3], pc[3];
    if (tid < HF) {
      if (role == 0) {
#pragma unroll
        for (int g = 0; g < 3; ++g) {
          const int rr = g * HF + tid;
          gw0[g] = W_ci[2 * rr]; gw1[g] = W_ci[2 * rr + 1]; gw2[g] = 0.f;
          gbe[g] = b_ci[rr] + gib[g * SZ + tid];
          pc[g] = cond[(((size_t)b * TT) * 3 + g) * SZ + tid];
        }
      } else {
#pragma unroll
        for (int g = 0; g < 3; ++g) {
          const int rr = g * HF + tid;
          gw0[g] = W_fi[3 * rr]; gw1[g] = W_fi[3 * rr + 1]; gw2[g] = W_fi[3 * rr + 2];
          gbe[g] = b_fi[rr] + gib[g * SZ + HF + tid];
          pc[g] = cond[(((size_t)b * TT) * 3 + g) * SZ + HF + tid];
        }
      }
      vlds[tid] = 0.f;
    }
    __syncthreads();
    float cvO = -1.f, fvO = -1.f;
    const float* hpSrc = (role ? g_hpf : g_hpc) + ((size_t)b * HF + (tid < HF ? tid : 0)) * 8;

    for (int t = 0; t < TT; ++t) {
      const uint2 kf = tf2(0u, 1u, 0u, (uint32_t)t);
      float gub = 0.f;
      if (tid < 64) {
        const uint2 kk = role ? tf2(kf.x, kf.y, 0u, 1u) : tf2(kf.x, kf.y, 0u, 0u);
        const uint2 o = tf2(kk.x, kk.y, 0u, (uint32_t)(b * 256 + 64 * k + tid));
        gub = gumbel_bits(o.x ^ o.y);
      }
      const uint32_t tgp = au((float)(t + 1));
      if (role == 0) {
        // ---- coarse WG: {bfl poll || cdone poll} -> hp verified load -> gates ----
        if (t > 0 && tid >= 452 && tid < 456) {
          const unsigned long long u = waitFlag64(&g_bfl[(b * 4 + (tid - 452)) * 8], (uint32_t)t);
          bS[tid - 452] = __uint_as_float((uint32_t)u);
          bI[tid - 452] = (int)((u >> 40) & 255u);
        }
        if (tid < NC) waitFlag(&g_cdone[tid * 16], (uint32_t)(t + 1));
        __syncthreads();
        float fvv = -1.f;
        if (t > 0) {
          float ms = bS[0]; int sf = bI[0];
#pragma unroll
          for (int m = 1; m < 4; ++m) {
            const float so = bS[m]; const int io = bI[m];
            if (so > ms || (so == ms && io < sf)) { ms = so; sf = io; }
          }
          fvv = (float)sf / 127.5f - 1.0f;
        }
        if (tid < HF) {
          f32x4 h0, h1;
          for (;;) {
            cload2x4(hpSrc, h0, h1);
            if (au(h0.y) >= tgp && au(h0.w) >= tgp && au(h1.y) >= tgp) break;
            __builtin_amdgcn_s_sleep(1);
          }
          const float cp0 = fmaf(cvO, gw0[0], fmaf(fvv, gw1[0], gbe[0])) + pc[0];
          const float cp1 = fmaf(cvO, gw0[1], fmaf(fvv, gw1[1], gbe[1])) + pc[1];
          const float cp2 = fmaf(cvO, gw0[2], fmaf(fvv, gw1[2], gbe[2])) + pc[2];
          const float rg = 1.f / (1.f + expf(-(cp0 + h0.x)));
          const float ug = 1.f / (1.f + expf(-(cp1 + h0.z)));
          const float eg = tanhf(fmaf(rg, h1.x, cp2));
          vlds[tid] = ug * vlds[tid] + (1.f - ug) * eg;
        }
        __syncthreads();
        if (k == 0 && tid < 112) {   // publish ch_t pairs (tag t+1), no drain
          const float tgf = (float)(t + 1);
          f32x4 p1, p2;
          p1.x = vlds[4 * tid];     p1.y = tgf; p1.z = vlds[4 * tid + 1]; p1.w = tgf;
          p2.x = vlds[4 * tid + 2]; p2.y = tgf; p2.z = vlds[4 * tid + 3]; p2.w = tgf;
          float* dst = g_hc + ((size_t)b * HF + 4 * tid) * 2;
          cstore4f_nw(dst, p1);
          cstore4f_nw(dst + 4, p2);
        }
        __builtin_amdgcn_s_barrier();
        if (k == 0 && tid == 0) cstore1u_nw(&g_chrdy[b * 16], (uint32_t)(t + 1));
        logits64(wlds, vlds, plds, tid);
        __syncthreads();
        if (tid < 64) {
          const float p0 = plds[tid],       p1 = plds[64 + tid];
          const float p2 = plds[128 + tid], p3 = plds[192 + tid];
          const float p4 = plds[256 + tid], p5 = plds[320 + tid];
          const float p6 = plds[384 + tid], p7 = plds[448 + tid];
          const float sum = ((p0 + p1) + (p2 + p3)) + ((p4 + p5) + (p6 + p7));
          float s = (sum + bias[64 * k + tid]) + gub;
          int idx = 64 * k + tid;
#pragma unroll
          for (int m = 1; m < 64; m <<= 1) {
            const float so = __shfl_xor(s, m);
            const int io = __shfl_xor(idx, m);
            if (so > s || (so == s && io < idx)) { s = so; idx = io; }
          }
          if (tid == 0) {
            f32x2 v; v.x = s;
            v.y = __uint_as_float(((uint32_t)(t + 1) << 16) | ((uint32_t)idx << 8));
            cstore2u_nw(&g_afl[(b * 4 + k) * 8], v);
          }
        }
        if (tid >= 448 && tid < 452) {
          const unsigned long long u = waitFlag64(&g_afl[(b * 4 + (tid - 448)) * 8], (uint32_t)(t + 1));
          aS[tid - 448] = __uint_as_float((uint32_t)u);
          aI[tid - 448] = (int)((u >> 40) & 255u);
        }
        __syncthreads();
        {
          float ms = aS[0]; int sc = aI[0];
#pragma unroll
          for (int m = 1; m < 4; ++m) {
            const float so = aS[m]; const int io = aI[m];
            if (so > ms || (so == ms && io < sc)) { ms = so; sc = io; }
          }
          cvO = (float)sc / 127.5f - 1.0f;
          if (k == 0 && tid == 0) out[b * TT + t] = (float)sc;
        }
        if (tid < HF && t + 1 < TT) {
#pragma unroll
          for (int g = 0; g < 3; ++g)
            pc[g] = cond[(((size_t)b * TT + (t + 1)) * 3 + g) * SZ + tid];
        }
      } else {
        // ---- fine WG: {cdone poll} -> hp load || afl poll -> sc -> gates ----
        if (tid < NC) waitFlag(&g_cdone[tid * 16], (uint32_t)(t + 1));
        __syncthreads();
        f32x4 h0 = {0.f, 0.f, 0.f, 0.f}, h1 = {0.f, 0.f, 0.f, 0.f};
        if (tid < HF) {
          for (;;) {
            cload2x4(hpSrc, h0, h1);
            if (au(h0.y) >= tgp && au(h0.w) >= tgp && au(h1.y) >= tgp) break;
            __builtin_amdgcn_s_sleep(1);
          }
        }
        if (tid >= 448 && tid < 452) {
          const unsigned long long u = waitFlag64(&g_afl[(b * 4 + (tid - 448)) * 8], (uint32_t)(t + 1));
          aS[tid - 448] = __uint_as_float((uint32_t)u);
          aI[tid - 448] = (int)((u >> 40) & 255u);
        }
        __syncthreads();
        float ms = aS[0]; int sc = aI[0];
#pragma unroll
        for (int m = 1; m < 4; ++m) {
          const float so = aS[m]; const int io = aI[m];
          if (so > ms || (so == ms && io < sc)) { ms = so; sc = io; }
        }
        const float cvNew = (float)sc / 127.5f - 1.0f;
        if (tid < HF) {
          const float fp0 = fmaf(cvO, gw0[0], fmaf(fvO, gw1[0], fmaf(cvNew, gw2[0], gbe[0]))) + pc[0];
          const float fp1 = fmaf(cvO, gw0[1], fmaf(fvO, gw1[1], fmaf(cvNew, gw2[1], gbe[1]))) + pc[1];
          const float fp2 = fmaf(cvO, gw0[2], fmaf(fvO, gw1[2], fmaf(cvNew, gw2[2], gbe[2]))) + pc[2];
          const float rg = 1.f / (1.f + expf(-(fp0 + h0.x)));
          const float ug = 1.f / (1.f + expf(-(fp1 + h0.z)));
          const float eg = tanhf(fmaf(rg, h1.x, fp2));
          vlds[tid] = ug * vlds[tid] + (1.f - ug) * eg;
        }
        __syncthreads();
        if (k == 0 && tid < 112) {   // publish fh_t pairs (tag t+1), no drain
          const float tgf = (float)(t + 1);
          f32x4 p1, p2;
          p1.x = vlds[4 * tid];     p1.y = tgf; p1.z = vlds[4 * tid + 1]; p1.w = tgf;
          p2.x = vlds[4 * tid + 2]; p2.y = tgf; p2.z = vlds[4 * tid + 3]; p2.w = tgf;
          float* dst = g_hf + ((size_t)b * HF + 4 * tid) * 2;
          cstore4f_nw(dst, p1);
          cstore4f_nw(dst + 4, p2);
        }
        __builtin_amdgcn_s_barrier();
        if (k == 0 && tid == 0) cstore1u_nw(&g_fhrdy[b * 16], (uint32_t)(t + 1));
        logits64(wlds, vlds, plds, tid);
        __syncthreads();
        if (tid < 64) {
          const float p0 = plds[tid],       p1 = plds[64 + tid];
          const float p2 = plds[128 + tid], p3 = plds[192 + tid];
          const float p4 = plds[256 + tid], p5 = plds[320 + tid];
          const float p6 = plds[384 + tid], p7 = plds[448 + tid];
          const float sum = ((p0 + p1) + (p2 + p3)) + ((p4 + p5) + (p6 + p7));
          float s = (sum + bias[64 * k + tid]) + gub;
          int idx = 64 * k + tid;
#pragma unroll
          for (int m = 1; m < 64; m <<= 1) {
            const float so = __shfl_xor(s, m);
            const int io = __shfl_xor(idx, m);
            if (so > s || (so == s && io < idx)) { s = so; idx = io; }
          }
          if (tid == 0) {
            f32x2 v; v.x = s;
            v.y = __uint_as_float(((uint32_t)(t + 1) << 16) | ((uint32_t)idx << 8));
            cstore2u_nw(&g_bfl[(b * 4 + k) * 8], v);
          }
        }
        if (tid >= 448 && tid < 452) {
          const unsigned long long u = waitFlag64(&g_bfl[(b * 4 + (tid - 448)) * 8], (uint32_t)(t + 1));
          bS[tid - 448] = __uint_as_float((uint32_t)u);
          bI[tid - 448] = (int)((u >> 40) & 255u);
        }
        __syncthreads();
        {
          float msf = bS[0]; int sf = bI[0];
#pragma unroll
          for (int m = 1; m < 4; ++m) {
            const float so = bS[m]; const int io = bI[m];
            if (so > msf || (so == msf && io < sf)) { msf = so; sf = io; }
          }
          fvO = (float)sf / 127.5f - 1.0f;
          if (k == 0 && tid == 0) out[BB * TT + b * TT + t] = (float)sf;
        }
        cvO = cvNew;
        if (tid < HF && t + 1 < TT) {
#pragma unroll
          for (int g = 0; g < 3; ++g)
            pc[g] = cond[(((size_t)b * TT + (t + 1)) * 3 + g) * SZ + HF + tid];
        }
      }
    }
    // final hidden from LDS state
    if (k == 0 && tid < HF) {
      if (role == 0) out[2 * BB * TT + (size_t)b * SZ + tid] = vlds[tid];
      else           out[2 * BB * TT + (size_t)b * SZ + HF + tid] = vlds[tid];
    }
  }
}

extern "C" void kernel_launch(void* const* d_in, const int* in_sizes, int n_in,
                              void* d_out, int out_size, void* d_ws, size_t ws_size,
                              hipStream_t stream) {
  (void)in_sizes; (void)n_in; (void)out_size; (void)d_ws; (void)ws_size;
  const float* cond = (const float*)d_in[0];
  const float* gib  = (const float*)d_in[1];
  const float* W_h  = (const float*)d_in[2];
  const float* b_h  = (const float*)d_in[3];
  const float* W_ci = (const float*)d_in[4];
  const float* b_ci = (const float*)d_in[5];
  const float* W_fi = (const float*)d_in[6];
  const float* b_fi = (const float*)d_in[7];
  const float* W_bc = (const float*)d_in[8];
  const float* b_bc = (const float*)d_in[9];
  const float* W_bf = (const float*)d_in[10];
  const float* b_bf = (const float*)d_in[11];
  float* out = (float*)d_out;
  hipFuncSetAttribute((const void*)wavernn_main,
                      hipFuncAttributeMaxDynamicSharedMemorySize, LDS_BYTES);
  wavernn_init<<<NC, 512, 0, stream>>>();
  wavernn_main<<<NWG, 512, LDS_BYTES, stream>>>(cond, gib, W_h, b_h, W_ci, b_ci,
                                                W_fi, b_fi, W_bc, b_bc, W_bf, b_bf, out);
}

// Round 11
// 12154.613 us; speedup vs baseline: 1.6703x; 1.1710x over previous
//
#include <hip/hip_runtime.h>
#include <stdint.h>

#define BB 16
#define TT 1000
#define SZ 896
#define HF 448
#define NC 112            // compute WGs (4 channels each, 8 waves of 1 task)
#define NWG 240           // 112 compute + 128 sampler (16 batches x (4 coarse + 4 fine))
#define LDS_FLOATS 30112
#define LDS_BYTES (LDS_FLOATS * 4)

typedef float f32x4 __attribute__((ext_vector_type(4)));
typedef float f32x2 __attribute__((ext_vector_type(2)));

// Persistent device-global state.
__device__ float g_hid[2 * BB * SZ];     // double-buffered hidden [2][16][896]
__device__ float g_hpf4[HF * BB * 4];    // fine hp rows [448][16][4] = {h_r,h_u,h_e,pad}
__device__ uint32_t g_cdone[NC * 16];    // compute flags: value = t+1
__device__ uint32_t g_fhd[BB * 16];      // F0 fh published: ((t+1)<<8)|sc
__device__ uint32_t g_sfd[BB * 16];      // F0 fine sample: ((t+1)<<8)|sf
__device__ unsigned long long g_afl[BB * 4 * 8];  // coarse candidates {score, (t+1)<<16|bin<<8}
__device__ unsigned long long g_bfl[BB * 4 * 8];  // fine candidates

// ---- pipelined coherent (L2-bypassing) loads/stores ----
__device__ __forceinline__ void cload4x4(const float* p, f32x4& a0, f32x4& a1, f32x4& a2, f32x4& a3) {
  asm volatile(
      "global_load_dwordx4 %0, %4, off sc0 sc1\n\t"
      "global_load_dwordx4 %1, %4, off offset:16 sc0 sc1\n\t"
      "global_load_dwordx4 %2, %4, off offset:32 sc0 sc1\n\t"
      "global_load_dwordx4 %3, %4, off offset:48 sc0 sc1\n\t"
      "s_waitcnt vmcnt(0)"
      : "=&v"(a0), "=&v"(a1), "=&v"(a2), "=&v"(a3) : "v"(p) : "memory");
}
__device__ __forceinline__ f32x4 cload1x4(const float* p) {
  f32x4 a;
  asm volatile("global_load_dwordx4 %0, %1, off sc0 sc1\n\ts_waitcnt vmcnt(0)"
               : "=&v"(a) : "v"(p) : "memory");
  return a;
}
__device__ __forceinline__ void cstore1d(float* p, float v) {
  asm volatile("global_store_dword %0, %1, off sc0 sc1\n\ts_waitcnt vmcnt(0)"
               :: "v"(p), "v"(v) : "memory");
}
__device__ __forceinline__ void cstore4d(float* p, f32x4 v) {
  asm volatile("global_store_dwordx4 %0, %1, off sc0 sc1\n\ts_waitcnt vmcnt(0)"
               :: "v"(p), "v"(v) : "memory");
}
__device__ __forceinline__ void cstore1u_nw(uint32_t* p, uint32_t v) {
  asm volatile("global_store_dword %0, %1, off sc0 sc1" :: "v"(p), "v"(v) : "memory");
}
__device__ __forceinline__ void cstore2u_nw(unsigned long long* p, f32x2 v) {
  asm volatile("global_store_dwordx2 %0, %1, off sc0 sc1" :: "v"(p), "v"(v) : "memory");
}

__device__ __forceinline__ void waitFlag(uint32_t* f, uint32_t target) {
  while (__hip_atomic_load(f, __ATOMIC_RELAXED, __HIP_MEMORY_SCOPE_AGENT) < target)
    __builtin_amdgcn_s_sleep(1);
}
__device__ __forceinline__ void waitFlagA(uint32_t* f, uint32_t target) {
  while (__hip_atomic_load(f, __ATOMIC_RELAXED, __HIP_MEMORY_SCOPE_AGENT) < target)
    __builtin_amdgcn_s_sleep(2);
}
__device__ __forceinline__ unsigned long long waitFlag64(unsigned long long* f, uint32_t tag) {
  unsigned long long u;
  while ((uint32_t)((u = __hip_atomic_load(f, __ATOMIC_RELAXED, __HIP_MEMORY_SCOPE_AGENT)) >> 48) < tag)
    __builtin_amdgcn_s_sleep(1);
  return u;
}
__device__ __forceinline__ uint32_t waitFlagHi8(uint32_t* f, uint32_t tag) {
  uint32_t v;
  while (((v = __hip_atomic_load(f, __ATOMIC_RELAXED, __HIP_MEMORY_SCOPE_AGENT)) >> 8) < tag)
    __builtin_amdgcn_s_sleep(1);
  return v;
}

__device__ __forceinline__ uint32_t rotl32(uint32_t v, int d) {
  return (v << d) | (v >> (32 - d));
}

// JAX threefry2x32 (20 rounds), bit-exact
__device__ __forceinline__ uint2 tf2(uint32_t k0, uint32_t k1, uint32_t x0, uint32_t x1) {
  const uint32_t k2 = k0 ^ k1 ^ 0x1BD11BDAu;
  x0 += k0; x1 += k1;
  x0 += x1; x1 = rotl32(x1,13); x1 ^= x0;
  x0 += x1; x1 = rotl32(x1,15); x1 ^= x0;
  x0 += x1; x1 = rotl32(x1,26); x1 ^= x0;
  x0 += x1; x1 = rotl32(x1, 6); x1 ^= x0;
  x0 += k1; x1 += k2 + 1u;
  x0 += x1; x1 = rotl32(x1,17); x1 ^= x0;
  x0 += x1; x1 = rotl32(x1,29); x1 ^= x0;
  x0 += x1; x1 = rotl32(x1,16); x1 ^= x0;
  x0 += x1; x1 = rotl32(x1,24); x1 ^= x0;
  x0 += k2; x1 += k0 + 2u;
  x0 += x1; x1 = rotl32(x1,13); x1 ^= x0;
  x0 += x1; x1 = rotl32(x1,15); x1 ^= x0;
  x0 += x1; x1 = rotl32(x1,26); x1 ^= x0;
  x0 += x1; x1 = rotl32(x1, 6); x1 ^= x0;
  x0 += k0; x1 += k1 + 3u;
  x0 += x1; x1 = rotl32(x1,17); x1 ^= x0;
  x0 += x1; x1 = rotl32(x1,29); x1 ^= x0;
  x0 += x1; x1 = rotl32(x1,16); x1 ^= x0;
  x0 += x1; x1 = rotl32(x1,24); x1 ^= x0;
  x0 += k1; x1 += k2 + 4u;
  x0 += x1; x1 = rotl32(x1,13); x1 ^= x0;
  x0 += x1; x1 = rotl32(x1,15); x1 ^= x0;
  x0 += x1; x1 = rotl32(x1,26); x1 ^= x0;
  x0 += x1; x1 = rotl32(x1, 6); x1 ^= x0;
  x0 += k2; x1 += k0 + 5u;
  return make_uint2(x0, x1);
}

__device__ __forceinline__ float gumbel_bits(uint32_t bits) {
  const float tiny = 1.17549435e-38f;
  float f = __uint_as_float((bits >> 9) | 0x3f800000u) - 1.0f;
  float u = fmaxf(tiny, f + tiny);
  return -logf(-logf(u));
}

// 64-bin logit partials from LDS-resident weight slice wlds[448][65] (padded).
// Wave w covers K in [56w, 56w+56); lane = local bin. Bit-identical chain order.
__device__ __forceinline__ void logits64(const float* __restrict__ wlds,
                                         const float* __restrict__ vec,
                                         float* __restrict__ plds, int tid) {
  const int w = tid >> 6, lane = tid & 63;
  float a = 0.f;
  const float* wp = wlds + (56 * w) * 65 + lane;
  const float* cp = vec + 56 * w;
#pragma unroll 8
  for (int ii = 0; ii < 56; ++ii)
    a = fmaf(cp[ii], wp[ii * 65], a);
  plds[(w << 6) | lane] = a;
}

__global__ __launch_bounds__(256, 1) void wavernn_init() {
  const int idx = blockIdx.x * 256 + threadIdx.x;   // 112 x 256 = 28672
  g_hid[idx] = 0.f;
  if (idx < NC * 16) g_cdone[idx] = 0u;
  if (idx < BB * 16) { g_fhd[idx] = 0u; g_sfd[idx] = 0u; }
  if (idx < BB * 4 * 8) { g_afl[idx] = 0ull; g_bfl[idx] = 0ull; }
}

__global__ __launch_bounds__(512, 1) void wavernn_main(
    const float* __restrict__ cond, const float* __restrict__ gib,
    const float* __restrict__ W_h,  const float* __restrict__ b_h,
    const float* __restrict__ W_ci, const float* __restrict__ b_ci,
    const float* __restrict__ W_fi, const float* __restrict__ b_fi,
    const float* __restrict__ W_bc, const float* __restrict__ b_bc,
    const float* __restrict__ W_bf, const float* __restrict__ b_bf,
    float* __restrict__ out) {
  extern __shared__ float smem[];
  const int wg = blockIdx.x, tid = threadIdx.x;

  if (wg < NC) {
    // ================= compute role: 8 waves, wave w = (type w>>2, chan wg*4+(w&3)) ======
    float* hlds = smem;                       // [16][900]
    int* smcv = (int*)(smem + 14400);         // [16]
    int* smfv = (int*)(smem + 14416);         // [16]
    const int wave = tid >> 6, lane = tid & 63;
    const int l32 = lane >> 1, b2 = lane & 1;
    const int tp = wave >> 2;                 // 0=coarse rows, 1=fine rows
    const int chan = (wg << 2) | (wave & 3);  // 0..447
    const int rb = tp ? (HF + chan) : chan;
    float4 w[3][7];
    float brow[3];
#pragma unroll
    for (int r = 0; r < 3; ++r) {
      const int row = r * SZ + rb;
      brow[r] = b_h[row];
#pragma unroll
      for (int m = 0; m < 7; ++m)
        w[r][m] = *(const float4*)&W_h[(size_t)row * SZ + 4 * l32 + 128 * m];
    }
    float wci0[3], wci1[3], bcie[3];
    if (tp == 0) {
#pragma unroll
      for (int g = 0; g < 3; ++g) {
        const int rr = g * HF + chan;
        wci0[g] = W_ci[2 * rr]; wci1[g] = W_ci[2 * rr + 1];
        bcie[g] = b_ci[rr] + gib[g * SZ + chan];
      }
    }
    float pc0 = 0.f, pc1 = 0.f, pc2 = 0.f;
    if (tp == 0 && lane < 16) {
      const size_t base = (((size_t)lane * TT) * 3) * SZ + chan;
      pc0 = cond[base]; pc1 = cond[base + SZ]; pc2 = cond[base + 2 * SZ];
    }
    float chreg = 0.f;
    const int r16 = tid & 15, c28 = tid >> 4;   // staging coords (c28<28 active)

    for (int t = 0; t < TT; ++t) {
      const int p = (t & 1) ^ 1;   // hidden_{t-1}
      const int q = t & 1;         // ch_t / hpf_t destination
      // ---- Phase A: compute barrier; stage coarse half; coarse-K matvec
      if (tid < NC) waitFlagA(&g_cdone[tid * 16], (uint32_t)t);
      __syncthreads();
      if (c28 < 28) {
        const float* src = g_hid + (size_t)p * BB * SZ + r16 * SZ + c28 * 16;
        f32x4 a0, a1, a2, a3;
        cload4x4(src, a0, a1, a2, a3);
        float* dst = hlds + r16 * 900 + c28 * 16;
        *(f32x4*)(dst) = a0; *(f32x4*)(dst + 4) = a1;
        *(f32x4*)(dst + 8) = a2; *(f32x4*)(dst + 12) = a3;
      }
      __syncthreads();
      float acc[3][8];
#pragma unroll
      for (int r = 0; r < 3; ++r)
#pragma unroll
        for (int i = 0; i < 8; ++i) acc[r][i] = 0.f;
#pragma unroll
      for (int i = 0; i < 8; ++i) {
        const int b = b2 + 2 * i;
        const float* hb = hlds + b * 900 + 4 * l32;
        const float4 h0 = *(const float4*)(hb);
        const float4 h1 = *(const float4*)(hb + 128);
        const float4 h2 = *(const float4*)(hb + 256);
#pragma unroll
        for (int r = 0; r < 3; ++r) {
          float s = acc[r][i];
          s = fmaf(w[r][0].x, h0.x, s); s = fmaf(w[r][0].y, h0.y, s);
          s = fmaf(w[r][0].z, h0.z, s); s = fmaf(w[r][0].w, h0.w, s);
          s = fmaf(w[r][1].x, h1.x, s); s = fmaf(w[r][1].y, h1.y, s);
          s = fmaf(w[r][1].z, h1.z, s); s = fmaf(w[r][1].w, h1.w, s);
          s = fmaf(w[r][2].x, h2.x, s); s = fmaf(w[r][2].y, h2.y, s);
          s = fmaf(w[r][2].z, h2.z, s); s = fmaf(w[r][2].w, h2.w, s);
          acc[r][i] = s;
        }
        if (l32 < 16) {
          const float4 h3 = *(const float4*)(hb + 384);
#pragma unroll
          for (int r = 0; r < 3; ++r) {
            float s = acc[r][i];
            s = fmaf(w[r][3].x, h3.x, s); s = fmaf(w[r][3].y, h3.y, s);
            s = fmaf(w[r][3].z, h3.z, s); s = fmaf(w[r][3].w, h3.w, s);
            acc[r][i] = s;
          }
        }
      }
      // ---- Phase B1: fh_{t-1} published by F0s (payload sc_{t-1}); stage fine half
      if (tid < BB) {
        const uint32_t v = waitFlagHi8(&g_fhd[tid * 16], (uint32_t)t);
        smcv[tid] = (int)(v & 255u);
      }
      __syncthreads();
      if (c28 < 28) {
        const float* src = g_hid + (size_t)p * BB * SZ + r16 * SZ + HF + c28 * 16;
        f32x4 a0, a1, a2, a3;
        cload4x4(src, a0, a1, a2, a3);
        float* dst = hlds + r16 * 900 + HF + c28 * 16;
        *(f32x4*)(dst) = a0; *(f32x4*)(dst + 4) = a1;
        *(f32x4*)(dst + 8) = a2; *(f32x4*)(dst + 12) = a3;
      }
      __syncthreads();
#pragma unroll
      for (int i = 0; i < 8; ++i) {
        const int b = b2 + 2 * i;
        const float* hb = hlds + b * 900 + 4 * l32;
        if (l32 >= 16) {
          const float4 h3 = *(const float4*)(hb + 384);
#pragma unroll
          for (int r = 0; r < 3; ++r) {
            float s = acc[r][i];
            s = fmaf(w[r][3].x, h3.x, s); s = fmaf(w[r][3].y, h3.y, s);
            s = fmaf(w[r][3].z, h3.z, s); s = fmaf(w[r][3].w, h3.w, s);
            acc[r][i] = s;
          }
        }
        const float4 h4 = *(const float4*)(hb + 512);
        const float4 h5 = *(const float4*)(hb + 640);
        const float4 h6 = *(const float4*)(hb + 768);
#pragma unroll
        for (int r = 0; r < 3; ++r) {
          float s = acc[r][i];
          s = fmaf(w[r][4].x, h4.x, s); s = fmaf(w[r][4].y, h4.y, s);
          s = fmaf(w[r][4].z, h4.z, s); s = fmaf(w[r][4].w, h4.w, s);
          s = fmaf(w[r][5].x, h5.x, s); s = fmaf(w[r][5].y, h5.y, s);
          s = fmaf(w[r][5].z, h5.z, s); s = fmaf(w[r][5].w, h5.w, s);
          s = fmaf(w[r][6].x, h6.x, s); s = fmaf(w[r][6].y, h6.y, s);
          s = fmaf(w[r][6].z, h6.z, s); s = fmaf(w[r][6].w, h6.w, s);
          acc[r][i] = s;
        }
      }
#pragma unroll
      for (int r = 0; r < 3; ++r)
#pragma unroll
        for (int i = 0; i < 8; ++i) {
          float v = acc[r][i];
          v += __shfl_xor(v, 2);
          v += __shfl_xor(v, 4);
          v += __shfl_xor(v, 8);
          v += __shfl_xor(v, 16);
          v += __shfl_xor(v, 32);
          acc[r][i] = v;
        }
      // ---- Phase B2: sf_{t-1}; gates + publish
      if (tid < BB) {
        const uint32_t v = waitFlagHi8(&g_sfd[tid * 16], (uint32_t)t);
        smfv[tid] = (int)(v & 255u);
      }
      __syncthreads();
      if (lane < 16) {
        const int bb = lane, i = lane >> 1;
        const float s0 = acc[0][i] + brow[0];
        const float s1 = acc[1][i] + brow[1];
        const float s2 = acc[2][i] + brow[2];
        if (tp == 0) {
          const float cvv = (float)smcv[bb] / 127.5f - 1.0f;
          const float fvv = (float)smfv[bb] / 127.5f - 1.0f;
          const float cp0 = fmaf(cvv, wci0[0], fmaf(fvv, wci1[0], bcie[0])) + pc0;
          const float cp1 = fmaf(cvv, wci0[1], fmaf(fvv, wci1[1], bcie[1])) + pc1;
          const float cp2 = fmaf(cvv, wci0[2], fmaf(fvv, wci1[2], bcie[2])) + pc2;
          const float rg = 1.f / (1.f + expf(-(cp0 + s0)));
          const float ug = 1.f / (1.f + expf(-(cp1 + s1)));
          const float eg = tanhf(fmaf(rg, s2, cp2));
          const float chn = ug * chreg + (1.f - ug) * eg;
          chreg = chn;
          cstore1d(&g_hid[(size_t)q * BB * SZ + bb * SZ + chan], chn);
        } else {
          f32x4 hv; hv.x = s0; hv.y = s1; hv.z = s2; hv.w = 0.f;
          cstore4d(&g_hpf4[((size_t)chan * 16 + bb) * 4], hv);
        }
      }
      __syncthreads();
      if (tid == 0) cstore1u_nw(&g_cdone[wg * 16], (uint32_t)(t + 1));
      if (tp == 0 && lane < 16 && t + 1 < TT) {
        const size_t base = (((size_t)lane * TT + (t + 1)) * 3) * SZ + chan;
        pc0 = cond[base]; pc1 = cond[base + SZ]; pc2 = cond[base + 2 * SZ];
      }
    }
  } else {
    // ================= sampler role: 8 WGs/batch = 4 coarse-slice + 4 fine-slice =========
    const int swg = wg - NC;            // 0..127
    const int b = swg >> 3;
    const int role = (swg >> 2) & 1;    // 0 = coarse, 1 = fine
    const int k = swg & 3;              // 64-bin slice
    float* wlds = smem;                 // [448][65] padded weight slice
    float* vlds = smem + 29120;         // [448]: C: staged ch_t; F: local fh
    float* plds = smem + 29568;         // [8][64] K-partials
    float* aS = smem + 30080;           // [4]
    int*   aI = (int*)(smem + 30084);   // [4]
    float* bS = smem + 30088;           // [4]
    int*   bI = (int*)(smem + 30092);   // [4]
    // fill LDS weight slice (coalesced global reads, pad-65 conflict-free LDS writes)
    {
      const float* Wm = role ? W_bf : W_bc;
      for (int i = tid; i < HF * 64; i += 512) {
        const int bn = i / HF, kk = i - bn * HF;
        wlds[kk * 65 + bn] = Wm[(size_t)(64 * k + bn) * HF + kk];
      }
    }
    const float* bias = role ? b_bf : b_bc;
    // fine-role per-thread gate params (channel = tid < 448)
    float wf0[3], wf1[3], wf2[3], bfe[3];
    float cp0 = 0.f, cp1 = 0.f, cp2 = 0.f;
    if (role == 1 && tid < HF) {
#pragma unroll
      for (int g = 0; g < 3; ++g) {
        const int rr = g * HF + tid;
        wf0[g] = W_fi[3 * rr]; wf1[g] = W_fi[3 * rr + 1]; wf2[g] = W_fi[3 * rr + 2];
        bfe[g] = b_fi[rr] + gib[g * SZ + HF + tid];
      }
      const size_t cbase = (((size_t)b * TT) * 3) * SZ + HF + tid;
      cp0 = cond[cbase]; cp1 = cond[cbase + SZ]; cp2 = cond[cbase + 2 * SZ];
      vlds[tid] = 0.f;   // fh_{-1} = 0
    }
    __syncthreads();
    float cvO = -1.f, fvO = -1.f;

    for (int t = 0; t < TT; ++t) {
      const int q = t & 1;
      // per-step keys + gumbel for own bins (before any wait — off critical path)
      const uint2 kf = tf2(0u, 1u, 0u, (uint32_t)t);
      float gub = 0.f;
      if (tid < 64) {
        const uint2 kk = role ? tf2(kf.x, kf.y, 0u, 1u) : tf2(kf.x, kf.y, 0u, 0u);
        const uint2 o = tf2(kk.x, kk.y, 0u, (uint32_t)(b * 256 + 64 * k + tid));
        gub = gumbel_bits(o.x ^ o.y);
      }
      if (role == 0) {
        // ---------------- coarse-slice WG ----------------
        if (tid < NC) waitFlag(&g_cdone[tid * 16], (uint32_t)(t + 1));
        __syncthreads();
        if (tid < 112) {
          const f32x4 v = cload1x4(g_hid + (size_t)q * BB * SZ + b * SZ + 4 * tid);
          *(f32x4*)&vlds[4 * tid] = v;
        }
        __syncthreads();
        logits64(wlds, vlds, plds, tid);
        __syncthreads();
        if (tid < 64) {
          const float p0 = plds[tid],       p1 = plds[64 + tid];
          const float p2 = plds[128 + tid], p3 = plds[192 + tid];
          const float p4 = plds[256 + tid], p5 = plds[320 + tid];
          const float p6 = plds[384 + tid], p7 = plds[448 + tid];
          const float sum = ((p0 + p1) + (p2 + p3)) + ((p4 + p5) + (p6 + p7));
          float s = (sum + bias[64 * k + tid]) + gub;
          int idx = 64 * k + tid;
#pragma unroll
          for (int m = 1; m < 64; m <<= 1) {
            const float so = __shfl_xor(s, m);
            const int io = __shfl_xor(idx, m);
            if (so > s || (so == s && io < idx)) { s = so; idx = io; }
          }
          if (tid == 0) {
            f32x2 v; v.x = s;
            v.y = __uint_as_float(((uint32_t)(t + 1) << 16) | ((uint32_t)idx << 8));
            cstore2u_nw(&g_afl[(b * 4 + k) * 8], v);
          }
        }
        // vlds keeps ch_t; at t=999 it holds ch_999 for the final-hidden write
      } else {
        // ---------------- fine-slice WG ----------------
        if (tid < NC) waitFlag(&g_cdone[tid * 16], (uint32_t)(t + 1));
        __syncthreads();
        f32x4 hp = {0.f, 0.f, 0.f, 0.f};
        if (tid < HF) hp = cload1x4(g_hpf4 + ((size_t)tid * 16 + b) * 4);
        if (tid >= 448 && tid < 452) {   // idle threads poll the 4 coarse candidates
          const unsigned long long u = waitFlag64(&g_afl[(b * 4 + (tid - 448)) * 8], (uint32_t)(t + 1));
          aS[tid - 448] = __uint_as_float((uint32_t)u);
          aI[tid - 448] = (int)((u >> 40) & 255u);
        }
        __syncthreads();
        float ms = aS[0]; int sc = aI[0];
#pragma unroll
        for (int m = 1; m < 4; ++m) {
          const float so = aS[m]; const int io = aI[m];
          if (so > ms || (so == ms && io < sc)) { ms = so; sc = io; }
        }
        const float cvNew = (float)sc / 127.5f - 1.0f;
        if (tid < HF) {   // all 448 fine gates, redundantly per F-WG (bit-identical)
          const float fp0 = fmaf(cvO, wf0[0], fmaf(fvO, wf1[0], fmaf(cvNew, wf2[0], bfe[0]))) + cp0;
          const float fp1 = fmaf(cvO, wf0[1], fmaf(fvO, wf1[1], fmaf(cvNew, wf2[1], bfe[1]))) + cp1;
          const float fp2 = fmaf(cvO, wf0[2], fmaf(fvO, wf1[2], fmaf(cvNew, wf2[2], bfe[2]))) + cp2;
          const float fhold = vlds[tid];
          const float rg = 1.f / (1.f + expf(-(fp0 + hp.x)));
          const float ug = 1.f / (1.f + expf(-(fp1 + hp.y)));
          const float eg = tanhf(fmaf(rg, hp.z, fp2));
          vlds[tid] = ug * fhold + (1.f - ug) * eg;
        }
        __syncthreads();
        if (k == 0) {
          if (tid < 112)
            cstore4d(&g_hid[(size_t)q * BB * SZ + b * SZ + HF + 4 * tid], *(f32x4*)&vlds[4 * tid]);
          __syncthreads();
          if (tid == 0) cstore1u_nw(&g_fhd[b * 16], ((uint32_t)(t + 1) << 8) | (uint32_t)sc);
        }
        logits64(wlds, vlds, plds, tid);
        __syncthreads();
        if (tid < 64) {
          const float p0 = plds[tid],       p1 = plds[64 + tid];
          const float p2 = plds[128 + tid], p3 = plds[192 + tid];
          const float p4 = plds[256 + tid], p5 = plds[320 + tid];
          const float p6 = plds[384 + tid], p7 = plds[448 + tid];
          const float sum = ((p0 + p1) + (p2 + p3)) + ((p4 + p5) + (p6 + p7));
          float s = (sum + bias[64 * k + tid]) + gub;
          int idx = 64 * k + tid;
#pragma unroll
          for (int m = 1; m < 64; m <<= 1) {
            const float so = __shfl_xor(s, m);
            const int io = __shfl_xor(idx, m);
            if (so > s || (so == s && io < idx)) { s = so; idx = io; }
          }
          if (tid == 0) {
            f32x2 v; v.x = s;
            v.y = __uint_as_float(((uint32_t)(t + 1) << 16) | ((uint32_t)idx << 8));
            cstore2u_nw(&g_bfl[(b * 4 + k) * 8], v);
          }
        }
        if (tid >= 448 && tid < 452) {
          const unsigned long long u = waitFlag64(&g_bfl[(b * 4 + (tid - 448)) * 8], (uint32_t)(t + 1));
          bS[tid - 448] = __uint_as_float((uint32_t)u);
          bI[tid - 448] = (int)((u >> 40) & 255u);
        }
        __syncthreads();
        float msf = bS[0]; int sf = bI[0];
#pragma unroll
        for (int m = 1; m < 4; ++m) {
          const float so = bS[m]; const int io = bI[m];
          if (so > msf || (so == msf && io < sf)) { msf = so; sf = io; }
        }
        if (k == 0 && tid == 0) {
          out[b * TT + t] = (float)sc;
          out[BB * TT + b * TT + t] = (float)sf;
          cstore1u_nw(&g_sfd[b * 16], ((uint32_t)(t + 1) << 8) | (uint32_t)sf);
        }
        cvO = cvNew; fvO = (float)sf / 127.5f - 1.0f;
        if (tid < HF && t + 1 < TT) {
          const size_t cbase = (((size_t)b * TT + (t + 1)) * 3) * SZ + HF + tid;
          cp0 = cond[cbase]; cp1 = cond[cbase + SZ]; cp2 = cond[cbase + 2 * SZ];
        }
      }
    }
    // final hidden: C0 writes ch_999 (vlds), F0 writes fh_999 (vlds)
    if (k == 0) {
      if (role == 0) {
        if (tid < HF) out[2 * BB * TT + (size_t)b * SZ + tid] = vlds[tid];
      } else {
        if (tid < HF) out[2 * BB * TT + (size_t)b * SZ + HF + tid] = vlds[tid];
      }
    }
  }
}

extern "C" void kernel_launch(void* const* d_in, const int* in_sizes, int n_in,
                              void* d_out, int out_size, void* d_ws, size_t ws_size,
                              hipStream_t stream) {
  (void)in_sizes; (void)n_in; (void)out_size; (void)d_ws; (void)ws_size;
  const float* cond = (const float*)d_in[0];
  const float* gib  = (const float*)d_in[1];
  const float* W_h  = (const float*)d_in[2];
  const float* b_h  = (const float*)d_in[3];
  const float* W_ci = (const float*)d_in[4];
  const float* b_ci = (const float*)d_in[5];
  const float* W_fi = (const float*)d_in[6];
  const float* b_fi = (const float*)d_in[7];
  const float* W_bc = (const float*)d_in[8];
  const float* b_bc = (const float*)d_in[9];
  const float* W_bf = (const float*)d_in[10];
  const float* b_bf = (const float*)d_in[11];
  float* out = (float*)d_out;
  hipFuncSetAttribute((const void*)wavernn_main,
                      hipFuncAttributeMaxDynamicSharedMemorySize, LDS_BYTES);
  wavernn_init<<<NC, 256, 0, stream>>>();
  wavernn_main<<<NWG, 512, LDS_BYTES, stream>>>(cond, gib, W_h, b_h, W_ci, b_ci,
                                                W_fi, b_fi, W_bc, b_bc, W_bf, b_bf, out);
}